// Round 1
// baseline (323.600 us; speedup 1.0000x reference)
//
#include <hip/hip_runtime.h>

// SpectralConv2dRealFreq: B=16, Cin=Cout=64, H=W=128, modes=33 (k in [-16,16])
// out = Re( iDFT2_trunc( (DFT2_trunc(x)) * (wr + i*wi) ) ), separable 1/sqrt(N) DFTs.
//
// Round 0: correctness-first fp32 vector implementation.
//  - phase table built on device each launch (deterministic)
//  - forward: per-image block, H-transform (global coalesced reads, SGPR table)
//             then W-transform (register-tiled LDS dot products)
//  - mix: per-mode complex channel GEMM, 2x8 (b,o) register tile
//  - inverse: per-image block, Z kept in 66 regs, SGPR tables, coalesced stores

#define NB   16
#define NC   64
#define NO   64
#define NH   128
#define NW   128
#define NM   33     // modes per axis
#define MP   36     // padded modes (multiple of 4, cols 33..35 zero)
#define NIMG 1024   // NB*NC == NB*NO

// ---------------------------------------------------------------- phase table
// Tf[f*128 + x] = (cos, sin) of 2*pi*freq(f)*x/128, scaled by 1/sqrt(128)
// Tt[x*MP + f]  = same, transposed + padded (cols 33..35 = 0)
__global__ __launch_bounds__(256) void spc_table(float2* __restrict__ Tf,
                                                 float2* __restrict__ Tt) {
  int t = blockIdx.x * 256 + threadIdx.x;
  if (t >= NM * NH) return;
  int f = t >> 7;           // 0..32
  int x = t & 127;          // 0..127
  int freq = (f <= 16) ? f : f + 95;   // 17..32 -> 112..127 (== -16..-1 mod 128)
  int ph = (freq * x) & 127;           // exact integer phase mod N
  float ang = (float)ph * 0.04908738521234052f;   // 2*pi/128
  float s, c;
  sincosf(ang, &s, &c);
  const float sc = 0.08838834764831845f;          // 1/sqrt(128)
  c *= sc; s *= sc;
  Tf[f * NH + x] = make_float2(c, s);
  Tt[x * MP + f] = make_float2(c, s);
  if (f < 3) Tt[x * MP + NM + f] = make_float2(0.f, 0.f);  // zero pad cols
}

// ---------------------------------------------------------------- forward DFT
// X2[img][i][j] = sum_{n,m} x[img][n][m] * e^{-i th2(i,n)} * e^{-i th1(j,m)} / N
__global__ __launch_bounds__(128) void spc_fwd(const float* __restrict__ x,
                                               const float2* __restrict__ Tt,
                                               float2* __restrict__ X2) {
  __shared__ float2 Ts[NH * MP];   // table copy, [m][j] layout for lane-varying reads
  __shared__ float2 Ys[34 * NH];   // Y[i][m], row 33 zeroed (pad for 2i tiling)
  const int m = threadIdx.x;       // lane = column m
  const int img = blockIdx.x;      // b*64 + c
  for (int k = m; k < NH * MP; k += 128) Ts[k] = Tt[k];

  // stage A: Y[i][m] = sum_n x[n][m] * (c - i s)[i][n]
  const float* xp = x + (size_t)img * (NH * NW);
  float aR[NM], aI[NM];
#pragma unroll
  for (int i = 0; i < NM; ++i) { aR[i] = 0.f; aI[i] = 0.f; }
  for (int n = 0; n < NH; ++n) {
    float xv = xp[n * NW + m];                 // coalesced, read once
#pragma unroll
    for (int i = 0; i < NM; ++i) {
      float2 p = Tt[n * MP + i];               // uniform index -> s_load
      aR[i] = fmaf(xv, p.x, aR[i]);
      aI[i] = fmaf(-xv, p.y, aI[i]);
    }
  }
#pragma unroll
  for (int i = 0; i < NM; ++i) Ys[i * NH + m] = make_float2(aR[i], aI[i]);
  Ys[33 * NH + m] = make_float2(0.f, 0.f);
  __syncthreads();

  // stage B: X2[i][j] = sum_m Y[i][m] * (c - i s)[j][m]; tile 2i x 4j per task
  float2* X2p = X2 + (size_t)img * (NM * MP);
  for (int task = m; task < 17 * 9; task += 128) {
    int it = task / 9;
    int jt = task - 9 * it;
    int i0 = 2 * it, i1 = 2 * it + 1;          // i1 may be 33 (zero row)
    int j0 = 4 * jt;
    float ar0[4], ai0[4], ar1[4], ai1[4];
#pragma unroll
    for (int q = 0; q < 4; ++q) { ar0[q] = ai0[q] = ar1[q] = ai1[q] = 0.f; }
    for (int mm = 0; mm < NH; ++mm) {
      float2 y0 = Ys[i0 * NH + mm];
      float2 y1 = Ys[i1 * NH + mm];
      float4 pa = *reinterpret_cast<const float4*>(&Ts[mm * MP + j0]);
      float4 pb = *reinterpret_cast<const float4*>(&Ts[mm * MP + j0 + 2]);
      float cc[4] = {pa.x, pa.z, pb.x, pb.z};
      float ss[4] = {pa.y, pa.w, pb.y, pb.w};
#pragma unroll
      for (int q = 0; q < 4; ++q) {
        ar0[q] += y0.x * cc[q] + y0.y * ss[q];
        ai0[q] += y0.y * cc[q] - y0.x * ss[q];
        ar1[q] += y1.x * cc[q] + y1.y * ss[q];
        ai1[q] += y1.y * cc[q] - y1.x * ss[q];
      }
    }
#pragma unroll
    for (int q = 0; q < 4; ++q) X2p[i0 * MP + j0 + q] = make_float2(ar0[q], ai0[q]);
    if (i1 < NM) {
#pragma unroll
      for (int q = 0; q < 4; ++q) X2p[i1 * MP + j0 + q] = make_float2(ar1[q], ai1[q]);
    }
  }
}

// ---------------------------------------------------------------- channel mix
// K[b,o,i,j] = sum_c X2[b,c,i,j] * (wr + i wi)[c,o,i,j]
__global__ __launch_bounds__(256) void spc_mix(const float* __restrict__ wr,
                                               const float* __restrict__ wi,
                                               const float2* __restrict__ X2,
                                               float2* __restrict__ Kf) {
  const int t = threadIdx.x;
  const int o0 = blockIdx.x * 8;       // 8 o-tiles
  const int b0 = blockIdx.y * 2;       // 8 b-tiles
  const int idxp = blockIdx.z * 256 + t;
  if (idxp >= NM * MP) return;
  const int i = idxp / MP;
  const int j = idxp - MP * i;
  if (j >= NM) return;                 // padded columns
  const int widx = i * NM + j;
  float aR[2][8], aI[2][8];
#pragma unroll
  for (int bb = 0; bb < 2; ++bb)
#pragma unroll
    for (int oo = 0; oo < 8; ++oo) { aR[bb][oo] = 0.f; aI[bb][oo] = 0.f; }
  for (int c = 0; c < NC; ++c) {
    float2 xv0 = X2[(size_t)((b0 + 0) * NC + c) * (NM * MP) + idxp];
    float2 xv1 = X2[(size_t)((b0 + 1) * NC + c) * (NM * MP) + idxp];
#pragma unroll
    for (int oo = 0; oo < 8; ++oo) {
      float Rr = wr[(size_t)(c * NO + o0 + oo) * (NM * NM) + widx];
      float Ri = wi[(size_t)(c * NO + o0 + oo) * (NM * NM) + widx];
      aR[0][oo] = fmaf(xv0.x, Rr, fmaf(-xv0.y, Ri, aR[0][oo]));
      aI[0][oo] = fmaf(xv0.x, Ri, fmaf(xv0.y, Rr, aI[0][oo]));
      aR[1][oo] = fmaf(xv1.x, Rr, fmaf(-xv1.y, Ri, aR[1][oo]));
      aI[1][oo] = fmaf(xv1.x, Ri, fmaf(xv1.y, Rr, aI[1][oo]));
    }
  }
#pragma unroll
  for (int bb = 0; bb < 2; ++bb)
#pragma unroll
    for (int oo = 0; oo < 8; ++oo)
      Kf[(size_t)((b0 + bb) * NO + o0 + oo) * (NM * MP) + idxp] =
          make_float2(aR[bb][oo], aI[bb][oo]);
}

// ---------------------------------------------------------------- inverse DFT
// out[img][n][m] = Re( sum_{i,j} K[img][i][j] * e^{+i th2(i,n)} * e^{+i th1(j,m)} )
__global__ __launch_bounds__(128) void spc_inv(const float2* __restrict__ Kf,
                                               const float2* __restrict__ Tf,
                                               const float2* __restrict__ Tt,
                                               float* __restrict__ out) {
  __shared__ float2 Ts[NM * NH];   // [j][m]
  const int m = threadIdx.x;
  const int img = blockIdx.x;      // b*64 + o
  for (int k = m; k < NM * NH; k += 128) Ts[k] = Tf[k];
  __syncthreads();

  // stage B^-1: Z[i][m] = sum_j K[i][j] * (c + i s)[j][m]   (Z in registers)
  const float2* Kp = Kf + (size_t)img * (NM * MP);
  float Zr[NM], Zi[NM];
#pragma unroll
  for (int i = 0; i < NM; ++i) { Zr[i] = 0.f; Zi[i] = 0.f; }
  for (int j = 0; j < NM; ++j) {
    float2 p = Ts[j * NH + m];                 // lane-varying, conflict-free
#pragma unroll
    for (int i = 0; i < NM; ++i) {
      float2 k = Kp[i * MP + j];               // uniform index -> s_load
      Zr[i] += k.x * p.x - k.y * p.y;
      Zi[i] += k.x * p.y + k.y * p.x;
    }
  }

  // stage A^-1: out[n][m] = sum_i Zr[i]*c2[i][n] - Zi[i]*s2[i][n]
  float* op = out + (size_t)img * (NH * NW);
  for (int n = 0; n < NH; ++n) {
    float acc = 0.f;
#pragma unroll
    for (int i = 0; i < NM; ++i) {
      float2 p2 = Tt[n * MP + i];              // uniform index -> s_load
      acc = fmaf(Zr[i], p2.x, fmaf(-Zi[i], p2.y, acc));
    }
    op[n * NW + m] = acc;                      // coalesced
  }
}

// ---------------------------------------------------------------- launch
extern "C" void kernel_launch(void* const* d_in, const int* in_sizes, int n_in,
                              void* d_out, int out_size, void* d_ws, size_t ws_size,
                              hipStream_t stream) {
  const float* x  = (const float*)d_in[0];
  const float* wr = (const float*)d_in[1];
  const float* wi = (const float*)d_in[2];
  float* out = (float*)d_out;

  char* ws = (char*)d_ws;
  const size_t szTf = (size_t)NM * NH * sizeof(float2);    // 33792
  const size_t szTt = (size_t)NH * MP * sizeof(float2);    // 36864
  const size_t szX2 = (size_t)NIMG * NM * MP * sizeof(float2);  // ~9.7 MB
  float2* Tf = (float2*)(ws);
  float2* Tt = (float2*)(ws + szTf);
  float2* X2 = (float2*)(ws + szTf + szTt);
  float2* Kf = (float2*)(ws + szTf + szTt + szX2);
  // total workspace use: ~18.6 MB

  hipLaunchKernelGGL(spc_table, dim3(17), dim3(256), 0, stream, Tf, Tt);
  hipLaunchKernelGGL(spc_fwd, dim3(NIMG), dim3(128), 0, stream, x, Tt, X2);
  hipLaunchKernelGGL(spc_mix, dim3(8, 8, 5), dim3(256), 0, stream, wr, wi, X2, Kf);
  hipLaunchKernelGGL(spc_inv, dim3(NIMG), dim3(128), 0, stream, Kf, Tf, Tt, out);
}

// Round 2
// 250.386 us; speedup vs baseline: 1.2924x; 1.2924x over previous
//
#include <hip/hip_runtime.h>

// SpectralConv2dRealFreq: B=16, Cin=Cout=64, H=W=128, modes=33 (k in [-16,16])
// out = Re( iDFT2_trunc( (DFT2_trunc(x)) * (wr + i*wi) ) ), separable 1/sqrt(N) DFTs.
//
// Round 2: occupancy + bank-conflict fix.
//  - fwd/inv: 256-thread blocks, mode-range split across half-blocks,
//    phase tables read from global (L1-resident) instead of LDS copies,
//    Ys padded to stride 131 float2 (kills the 15-way row-bank conflict).
//  - mix: b-tile 4 (weights traffic halved), finer z-split for CU coverage.

#define NB   16
#define NC   64
#define NO   64
#define NH   128
#define NW   128
#define NM   33      // modes per axis
#define MP   36      // padded modes (cols 33..35 zero)
#define NMODE (NM*MP)   // 1188
#define WMODE (NM*NM)   // 1089
#define NIMG 1024
#define YLD  131     // Ys row stride in float2 (262 words: 6i mod 32 -> 16 spots)

// ---------------------------------------------------------------- phase table
// Tf[f*128 + x] = (cos, sin) of 2*pi*freq(f)*x/128, scaled by 1/sqrt(128)
// Tt[x*MP + f]  = same, transposed + padded (cols 33..35 = 0)
__global__ __launch_bounds__(256) void spc_table(float2* __restrict__ Tf,
                                                 float2* __restrict__ Tt) {
  int t = blockIdx.x * 256 + threadIdx.x;
  if (t >= NM * NH) return;
  int f = t >> 7;           // 0..32
  int x = t & 127;          // 0..127
  int freq = (f <= 16) ? f : f + 95;   // 17..32 -> 112..127 (== -16..-1 mod 128)
  int ph = (freq * x) & 127;           // exact integer phase mod N
  float ang = (float)ph * 0.04908738521234052f;   // 2*pi/128
  float s, c;
  sincosf(ang, &s, &c);
  const float sc = 0.08838834764831845f;          // 1/sqrt(128)
  c *= sc; s *= sc;
  Tf[f * NH + x] = make_float2(c, s);
  Tt[x * MP + f] = make_float2(c, s);
  if (f < 3) Tt[x * MP + NM + f] = make_float2(0.f, 0.f);  // zero pad cols
}

// ---------------------------------------------------------------- forward DFT
// X2[img][i][j] = sum_{n,m} x[img][n][m] * e^{-i th2(i,n)} * e^{-i th1(j,m)} / N
__global__ __launch_bounds__(256) void spc_fwd(const float* __restrict__ x,
                                               const float2* __restrict__ Tt,
                                               float2* __restrict__ X2) {
  __shared__ float2 Ys[34 * YLD];   // Y[i][m], padded stride; row 33 == zeros
  const int t = threadIdx.x;
  const int m = t & 127;
  const int h = __builtin_amdgcn_readfirstlane(t >> 7);  // wave-uniform half id
  const int ib = h * 17;            // i-range [ib, ib+17); i=33 hits zeroed pad col
  const int img = blockIdx.x;       // b*64 + c

  // stage A: Y[i][m] = sum_n x[n][m] * (c - i s)[i][n]
  const float* xp = x + (size_t)img * (NH * NW);
  float aR[17], aI[17];
#pragma unroll
  for (int q = 0; q < 17; ++q) { aR[q] = 0.f; aI[q] = 0.f; }
  for (int n = 0; n < NH; ++n) {
    float xv = xp[n * NW + m];                 // coalesced
#pragma unroll
    for (int q = 0; q < 17; ++q) {
      float2 p = Tt[n * MP + ib + q];          // wave-uniform -> scalar load
      aR[q] = fmaf(xv, p.x, aR[q]);
      aI[q] = fmaf(-xv, p.y, aI[q]);
    }
  }
#pragma unroll
  for (int q = 0; q < 17; ++q)
    Ys[(ib + q) * YLD + m] = make_float2(aR[q], aI[q]);
  __syncthreads();

  // stage B: X2[i][j] = sum_m Y[i][m] * (c - i s)[j][m]; tile 2i x 4j per lane
  float2* X2p = X2 + (size_t)img * NMODE;
  if (t < 17 * 9) {
    const int it = t / 9;
    const int jt = t - 9 * it;
    const int i0 = 2 * it, i1 = i0 + 1;        // i1 may be 33 (zero row)
    const int j0 = 4 * jt;
    float ar0[4], ai0[4], ar1[4], ai1[4];
#pragma unroll
    for (int q = 0; q < 4; ++q) { ar0[q] = ai0[q] = ar1[q] = ai1[q] = 0.f; }
    for (int mm = 0; mm < NH; ++mm) {
      float2 y0 = Ys[i0 * YLD + mm];
      float2 y1 = Ys[i1 * YLD + mm];
      float4 pa = *reinterpret_cast<const float4*>(&Tt[mm * MP + j0]);
      float4 pb = *reinterpret_cast<const float4*>(&Tt[mm * MP + j0 + 2]);
      float cc[4] = {pa.x, pa.z, pb.x, pb.z};
      float ss[4] = {pa.y, pa.w, pb.y, pb.w};
#pragma unroll
      for (int q = 0; q < 4; ++q) {
        ar0[q] += y0.x * cc[q] + y0.y * ss[q];
        ai0[q] += y0.y * cc[q] - y0.x * ss[q];
        ar1[q] += y1.x * cc[q] + y1.y * ss[q];
        ai1[q] += y1.y * cc[q] - y1.x * ss[q];
      }
    }
#pragma unroll
    for (int q = 0; q < 4; ++q) X2p[i0 * MP + j0 + q] = make_float2(ar0[q], ai0[q]);
    if (i1 < NM) {
#pragma unroll
      for (int q = 0; q < 4; ++q) X2p[i1 * MP + j0 + q] = make_float2(ar1[q], ai1[q]);
    }
  }
}

// ---------------------------------------------------------------- channel mix
// K[b,o,i,j] = sum_c X2[b,c,i,j] * (wr + i wi)[c,o,i,j]
__global__ __launch_bounds__(128) void spc_mix(const float* __restrict__ wr,
                                               const float* __restrict__ wi,
                                               const float2* __restrict__ X2,
                                               float2* __restrict__ Kf) {
  const int t = threadIdx.x;
  const int o0 = blockIdx.x * 8;       // 8 o-tiles
  const int b0 = blockIdx.y * 4;       // 4 b-tiles
  const int idxp = blockIdx.z * 128 + t;
  if (idxp >= NMODE) return;
  const int i = idxp / MP;
  const int j = idxp - MP * i;
  if (j >= NM) return;                 // padded columns
  const int widx = i * NM + j;
  float aR[4][8], aI[4][8];
#pragma unroll
  for (int bb = 0; bb < 4; ++bb)
#pragma unroll
    for (int oo = 0; oo < 8; ++oo) { aR[bb][oo] = 0.f; aI[bb][oo] = 0.f; }
  for (int c = 0; c < NC; ++c) {
    float2 xv[4];
#pragma unroll
    for (int bb = 0; bb < 4; ++bb)
      xv[bb] = X2[(size_t)((b0 + bb) * NC + c) * NMODE + idxp];
#pragma unroll
    for (int oo = 0; oo < 8; ++oo) {
      float Rr = wr[(size_t)(c * NO + o0 + oo) * WMODE + widx];
      float Ri = wi[(size_t)(c * NO + o0 + oo) * WMODE + widx];
#pragma unroll
      for (int bb = 0; bb < 4; ++bb) {
        aR[bb][oo] = fmaf(xv[bb].x, Rr, fmaf(-xv[bb].y, Ri, aR[bb][oo]));
        aI[bb][oo] = fmaf(xv[bb].x, Ri, fmaf(xv[bb].y, Rr, aI[bb][oo]));
      }
    }
  }
#pragma unroll
  for (int bb = 0; bb < 4; ++bb)
#pragma unroll
    for (int oo = 0; oo < 8; ++oo)
      Kf[(size_t)((b0 + bb) * NO + o0 + oo) * NMODE + idxp] =
          make_float2(aR[bb][oo], aI[bb][oo]);
}

// ---------------------------------------------------------------- inverse DFT
// out[img][n][m] = Re( sum_{i,j} K[img][i][j] * e^{+i th2(i,n)} * e^{+i th1(j,m)} )
__global__ __launch_bounds__(256) void spc_inv(const float2* __restrict__ Kf,
                                               const float2* __restrict__ Tf,
                                               const float2* __restrict__ Tt,
                                               float* __restrict__ out) {
  __shared__ float2 Zs[NM * NH];    // Z[i][m]
  const int t = threadIdx.x;
  const int m = t & 127;
  const int h = __builtin_amdgcn_readfirstlane(t >> 7);
  const int ib = h * 17;            // h0: i 0..16, h1: i 17..32 (+1 clamped dummy)
  const int img = blockIdx.x;       // b*64 + o
  const float2* Kp = Kf + (size_t)img * NMODE;

  // stage B^-1: Z[i][m] = sum_j K[i][j] * (c + i s)[j][m]
  float Zr[17], Zi[17];
#pragma unroll
  for (int q = 0; q < 17; ++q) { Zr[q] = 0.f; Zi[q] = 0.f; }
  for (int j = 0; j < NM; ++j) {
    float2 p = Tf[j * NH + m];                 // lane-varying, coalesced, L1-hot
#pragma unroll
    for (int q = 0; q < 17; ++q) {
      int iq = ib + q; if (iq > 32) iq = 32;   // clamp: h1's 17th row is a dummy
      float2 k = Kp[iq * MP + j];              // wave-uniform -> scalar load
      Zr[q] = fmaf(k.x, p.x, fmaf(-k.y, p.y, Zr[q]));
      Zi[q] = fmaf(k.x, p.y, fmaf(k.y, p.x, Zi[q]));
    }
  }
#pragma unroll
  for (int q = 0; q < 17; ++q) {
    if (h == 0 || q < 16)                      // don't store the dummy row
      Zs[(ib + q) * NH + m] = make_float2(Zr[q], Zi[q]);
  }
  __syncthreads();

  // pull full Z column into registers, then n-transform (half block = half n-range)
  float zr[NM], zi[NM];
#pragma unroll
  for (int i = 0; i < NM; ++i) {
    float2 z = Zs[i * NH + m];
    zr[i] = z.x; zi[i] = z.y;
  }
  float* op = out + (size_t)img * (NH * NW);
  const int n0 = h * 64;
  for (int nn = 0; nn < 64; ++nn) {
    const int n = n0 + nn;
    float acc = 0.f;
#pragma unroll
    for (int i = 0; i < NM; ++i) {
      float2 p2 = Tt[n * MP + i];              // wave-uniform -> scalar load
      acc = fmaf(zr[i], p2.x, fmaf(-zi[i], p2.y, acc));
    }
    op[n * NW + m] = acc;                      // coalesced
  }
}

// ---------------------------------------------------------------- launch
extern "C" void kernel_launch(void* const* d_in, const int* in_sizes, int n_in,
                              void* d_out, int out_size, void* d_ws, size_t ws_size,
                              hipStream_t stream) {
  const float* x  = (const float*)d_in[0];
  const float* wr = (const float*)d_in[1];
  const float* wi = (const float*)d_in[2];
  float* out = (float*)d_out;

  char* ws = (char*)d_ws;
  const size_t szTf = (size_t)NM * NH * sizeof(float2);         // 33792
  const size_t szTt = (size_t)NH * MP * sizeof(float2);         // 36864
  const size_t szX2 = (size_t)NIMG * NMODE * sizeof(float2);    // ~9.7 MB
  float2* Tf = (float2*)(ws);
  float2* Tt = (float2*)(ws + szTf);
  float2* X2 = (float2*)(ws + szTf + szTt);
  float2* Kf = (float2*)(ws + szTf + szTt + szX2);
  // total workspace use: ~19.5 MB

  hipLaunchKernelGGL(spc_table, dim3(17), dim3(256), 0, stream, Tf, Tt);
  hipLaunchKernelGGL(spc_fwd, dim3(NIMG), dim3(256), 0, stream, x, Tt, X2);
  hipLaunchKernelGGL(spc_mix, dim3(8, 4, 10), dim3(128), 0, stream, wr, wi, X2, Kf);
  hipLaunchKernelGGL(spc_inv, dim3(NIMG), dim3(256), 0, stream, Kf, Tf, Tt, out);
}

// Round 3
// 92.950 us; speedup vs baseline: 3.4815x; 2.6938x over previous
//
#include <hip/hip_runtime.h>

// SpectralConv2dRealFreq: B=16, Cin=Cout=64, H=W=128, modes=33 (k in [-16,16])
// out = Re( iDFT2_trunc( (DFT2_trunc(x)) * (wr + i*wi) ) ), separable 1/sqrt(N) DFTs.
//
// Round 3: bf16 MFMA for both transforms.
//   fwd:  G = Fh · x · Fw^T per image (Fh=[C;S] 80x128 padded), X2 from G quadrants
//   mix:  fp32 vector channel GEMM, writes U = [[Kr,-Ki],[-Ki,-Kr]] bf16 (80x96 pad)
//   inv:  out = Fh^T · U · Fw per image
// Phase tables are pre-stored in MFMA fragment layout; LDS transposes use an
// XOR granule swizzle applied identically on write and read (k-order cancels).

#define NB   16
#define NC   64
#define NO   64
#define NH   128
#define NW   128
#define NM   33
#define MP   36
#define NMODE (NM*MP)   // 1188
#define WMODE (NM*NM)   // 1089
#define NIMG 1024
#define UR   80         // U rows (66 padded)
#define UC   96         // U cols (66 padded to 3*32 for K-steps)
#define USZ  (UR*UC)    // 7680 bf16 per image

typedef __attribute__((ext_vector_type(8))) short s8v;   // 8 bf16 (4 VGPRs)
typedef __attribute__((ext_vector_type(4))) float f4v;   // MFMA accumulator

__device__ inline unsigned short f2bf(float f) {
  union { float f; unsigned u; } v; v.f = f;
  unsigned r = (v.u + 0x7FFFu + ((v.u >> 16) & 1u)) >> 16;   // RNE
  return (unsigned short)r;
}

__device__ inline s8v pack8(float4 a, float4 b) {
  s8v r;
  r[0] = (short)f2bf(a.x); r[1] = (short)f2bf(a.y);
  r[2] = (short)f2bf(a.z); r[3] = (short)f2bf(a.w);
  r[4] = (short)f2bf(b.x); r[5] = (short)f2bf(b.y);
  r[6] = (short)f2bf(b.z); r[7] = (short)f2bf(b.w);
  return r;
}

__device__ inline uint2 pack4(f4v a) {
  uint2 p;
  p.x = (unsigned)f2bf(a[0]) | ((unsigned)f2bf(a[1]) << 16);
  p.y = (unsigned)f2bf(a[2]) | ((unsigned)f2bf(a[3]) << 16);
  return p;
}

// stacked-phase value: f in [0,33): cos row f; [33,66): sin row f-33; >=66: 0
__device__ inline unsigned short phase_bf(int f, int x) {
  if (f >= 66) return 0;
  int g = (f < 33) ? f : f - 33;
  int fr = (g <= 16) ? g : g + 95;          // signed freq mod 128
  int ph = (fr * x) & 127;                  // exact integer phase
  float ang = (float)ph * 0.04908738521234052f;   // 2*pi/128
  float v = ((f < 33) ? cosf(ang) : sinf(ang)) * 0.08838834764831845f;  // /sqrt(128)
  return f2bf(v);
}

// --------------------------------------------------- fragment-layout tables
// T1 fwd-B : [ks<4][jt<5][l][e] = Pw(f=jt*16+(l&15),      x=ks*32+(l>>4)*8+e)
// T2 fwd-A : [it<5][ks<4][l][e] = Ph(f=it*16+(l&15),      x=ks*32+(l>>4)*8+e)
// T3 inv-B : [ks<3][mt<8][l][e] = Pw(f=ks*32+(l>>4)*8+e,  x=mt*16+(l&15))
// T4 inv-A : [nt<8][ks<3][l][e] = Ph(f=ks*32+(l>>4)*8+e,  x=nt*16+(l&15))
__global__ __launch_bounds__(256) void spc_tables(short* __restrict__ T1,
                                                  short* __restrict__ T2,
                                                  short* __restrict__ T3,
                                                  short* __restrict__ T4) {
  int tid = blockIdx.x * 256 + threadIdx.x;
  if (tid >= 45056) return;
  int f, x; short* dst;
  if (tid < 10240) {
    int e = tid & 7, l = (tid >> 3) & 63, q = tid >> 9;     // q = ks*5+jt
    int ks = q / 5, jt = q - 5 * ks;
    f = jt * 16 + (l & 15); x = ks * 32 + (l >> 4) * 8 + e; dst = T1 + tid;
  } else if (tid < 20480) {
    int u = tid - 10240;
    int e = u & 7, l = (u >> 3) & 63, q = u >> 9;           // q = it*4+ks
    int it = q / 4, ks = q - 4 * it;
    f = it * 16 + (l & 15); x = ks * 32 + (l >> 4) * 8 + e; dst = T2 + u;
  } else if (tid < 32768) {
    int u = tid - 20480;
    int e = u & 7, l = (u >> 3) & 63, q = u >> 9;           // q = ks*8+mt
    int ks = q / 8, mt = q - 8 * ks;
    f = ks * 32 + (l >> 4) * 8 + e; x = mt * 16 + (l & 15); dst = T3 + u;
  } else {
    int u = tid - 32768;
    int e = u & 7, l = (u >> 3) & 63, q = u >> 9;           // q = nt*3+ks
    int nt = q / 3, ks = q - 3 * nt;
    f = ks * 32 + (l >> 4) * 8 + e; x = nt * 16 + (l & 15); dst = T4 + u;
  }
  *dst = (short)phase_bf(f, x);
}

// zero U padding: rows 66..79 and cols 66..95 (mix fills the quadrants)
__global__ __launch_bounds__(256) void spc_padU(short* __restrict__ U) {
  short* Up = U + (size_t)blockIdx.x * USZ;
  for (int idx = threadIdx.x; idx < USZ; idx += 256) {
    int i = idx / UC, j = idx - UC * i;
    if (i >= 66 || j >= 66) Up[idx] = 0;
  }
}

// --------------------------------------------------------------- forward DFT
__global__ __launch_bounds__(256) void spc_fwd_mfma(const float* __restrict__ x,
                                                    const s8v* __restrict__ T1,
                                                    const s8v* __restrict__ T2,
                                                    float2* __restrict__ X2) {
  __shared__ short Wt[80 * 128];   // W1T[j][n] bf16, granule-4 XOR swizzle
  __shared__ float Gs[80 * 84];    // G f32, stride 84
  const int t = threadIdx.x;
  const int l = t & 63;
  const int w = t >> 6;
  const int lr = l & 15;           // A-row / B-col / D-col lane index
  const int lg = l >> 4;           // k-group
  const int img = blockIdx.x;
  const float* xp = x + (size_t)img * (NH * NW);

  // stage 1: W1[n][j] = sum_m x[n][m] * Fw[j][m]; tiles (nt=2w..2w+1, jt 0..4)
  for (int nn = 0; nn < 2; ++nn) {
    const int nt = 2 * w + nn;
    const float* xrow = xp + (nt * 16 + lr) * NW + lg * 8;
    s8v a[4];
#pragma unroll
    for (int ks = 0; ks < 4; ++ks) {
      float4 f0 = *reinterpret_cast<const float4*>(xrow + ks * 32);
      float4 f1 = *reinterpret_cast<const float4*>(xrow + ks * 32 + 4);
      a[ks] = pack8(f0, f1);
    }
#pragma unroll
    for (int jt = 0; jt < 5; ++jt) {
      f4v acc = {0.f, 0.f, 0.f, 0.f};
#pragma unroll
      for (int ks = 0; ks < 4; ++ks) {
        s8v b = T1[(ks * 5 + jt) * 64 + l];
        acc = __builtin_amdgcn_mfma_f32_16x16x32_bf16(a[ks], b, acc, 0, 0, 0);
      }
      // D: n = nt*16+lg*4+r, j = jt*16+lr  ->  Wt[j][n] (transposed, swizzled)
      int j = jt * 16 + lr;
      int g = ((nt * 16 + lg * 4) >> 2) ^ ((j & 7) << 2);
      *reinterpret_cast<uint2*>(&Wt[j * 128 + g * 4]) = pack4(acc);
    }
  }
  __syncthreads();

  // stage 2: G[i][j] = sum_n Fh[i][n] * W1[n][j]; 25 tiles round-robin
  for (int tix = w; tix < 25; tix += 4) {
    int it = tix / 5, j2 = tix - 5 * it;
    int jrow = j2 * 16 + lr;
    f4v acc = {0.f, 0.f, 0.f, 0.f};
#pragma unroll
    for (int ks = 0; ks < 4; ++ks) {
      s8v afr = T2[(it * 4 + ks) * 64 + l];
      int g = (ks * 8 + lg * 2) ^ ((jrow & 7) << 2);
      s8v b = *reinterpret_cast<const s8v*>(&Wt[jrow * 128 + g * 4]);
      acc = __builtin_amdgcn_mfma_f32_16x16x32_bf16(afr, b, acc, 0, 0, 0);
    }
    int gi = it * 16 + lg * 4;
#pragma unroll
    for (int r = 0; r < 4; ++r) Gs[(gi + r) * 84 + jrow] = acc[r];
  }
  __syncthreads();

  // epilogue: X2r = G11 - G22, X2i = -(G12 + G21)
  float2* X2p = X2 + (size_t)img * NMODE;
  for (int idx = t; idx < WMODE; idx += 256) {
    int i = idx / 33, j = idx - 33 * i;
    float g11 = Gs[i * 84 + j];
    float g22 = Gs[(i + 33) * 84 + (j + 33)];
    float g12 = Gs[i * 84 + (j + 33)];
    float g21 = Gs[(i + 33) * 84 + j];
    X2p[i * MP + j] = make_float2(g11 - g22, -(g12 + g21));
  }
}

// ---------------------------------------------------------------- channel mix
// K[b,o,i,j] = sum_c X2[b,c,i,j] * (wr + i wi)[c,o,i,j]; writes U quadrants bf16
__global__ __launch_bounds__(128) void spc_mix(const float* __restrict__ wr,
                                               const float* __restrict__ wi,
                                               const float2* __restrict__ X2,
                                               short* __restrict__ U) {
  const int t = threadIdx.x;
  const int o0 = blockIdx.x * 4;       // 16 o-tiles
  const int b0 = blockIdx.y * 4;       // 4 b-tiles
  const int idxp = blockIdx.z * 128 + t;
  if (idxp >= NMODE) return;
  const int i = idxp / MP;
  const int j = idxp - MP * i;
  if (j >= NM) return;
  const int widx = i * NM + j;
  float aR[4][4], aI[4][4];
#pragma unroll
  for (int bb = 0; bb < 4; ++bb)
#pragma unroll
    for (int oo = 0; oo < 4; ++oo) { aR[bb][oo] = 0.f; aI[bb][oo] = 0.f; }
  for (int c = 0; c < NC; ++c) {
    float2 xv[4];
#pragma unroll
    for (int bb = 0; bb < 4; ++bb)
      xv[bb] = X2[(size_t)((b0 + bb) * NC + c) * NMODE + idxp];
#pragma unroll
    for (int oo = 0; oo < 4; ++oo) {
      float Rr = wr[(size_t)(c * NO + o0 + oo) * WMODE + widx];
      float Ri = wi[(size_t)(c * NO + o0 + oo) * WMODE + widx];
#pragma unroll
      for (int bb = 0; bb < 4; ++bb) {
        aR[bb][oo] = fmaf(xv[bb].x, Rr, fmaf(-xv[bb].y, Ri, aR[bb][oo]));
        aI[bb][oo] = fmaf(xv[bb].x, Ri, fmaf(xv[bb].y, Rr, aI[bb][oo]));
      }
    }
  }
#pragma unroll
  for (int bb = 0; bb < 4; ++bb)
#pragma unroll
    for (int oo = 0; oo < 4; ++oo) {
      size_t base = (size_t)((b0 + bb) * NO + o0 + oo) * USZ;
      unsigned short kr  = f2bf(aR[bb][oo]);
      unsigned short nkr = f2bf(-aR[bb][oo]);
      unsigned short nki = f2bf(-aI[bb][oo]);
      U[base + i * UC + j]               = (short)kr;
      U[base + i * UC + (j + 33)]        = (short)nki;
      U[base + (i + 33) * UC + j]        = (short)nki;
      U[base + (i + 33) * UC + (j + 33)] = (short)nkr;
    }
}

// ---------------------------------------------------------------- inverse DFT
__global__ __launch_bounds__(256) void spc_inv_mfma(const short* __restrict__ U,
                                                    const s8v* __restrict__ T3,
                                                    const s8v* __restrict__ T4,
                                                    float* __restrict__ out) {
  __shared__ short Vt[128 * 128];   // VT[m][i'] bf16, granule-4 XOR swizzle
  const int t = threadIdx.x;
  const int l = t & 63;
  const int w = t >> 6;
  const int lr = l & 15;
  const int lg = l >> 4;
  const int img = blockIdx.x;

  // zero VT (covers i' 80..95 K-padding and swizzle holes)
  for (int k = t; k < (128 * 128) / 8; k += 256)
    reinterpret_cast<uint4*>(Vt)[k] = uint4{0u, 0u, 0u, 0u};
  __syncthreads();

  const short* Up = U + (size_t)img * USZ;

  // stage 1: V[i'][m] = sum_j U[i'][j] * Fw[j][m]; tiles (it 0..4, mt=2w..2w+1)
  for (int mm = 0; mm < 2; ++mm) {
    const int mt = 2 * w + mm;
    s8v b[3];
#pragma unroll
    for (int ks = 0; ks < 3; ++ks) b[ks] = T3[(ks * 8 + mt) * 64 + l];
    for (int it = 0; it < 5; ++it) {
      f4v acc = {0.f, 0.f, 0.f, 0.f};
#pragma unroll
      for (int ks = 0; ks < 3; ++ks) {
        s8v a = *reinterpret_cast<const s8v*>(Up + (it * 16 + lr) * UC + ks * 32 + lg * 8);
        acc = __builtin_amdgcn_mfma_f32_16x16x32_bf16(a, b[ks], acc, 0, 0, 0);
      }
      // D: i' = it*16+lg*4+r, m = mt*16+lr  ->  Vt[m][i'] swizzled
      int m = mt * 16 + lr;
      int g = ((it * 16 + lg * 4) >> 2) ^ ((m & 7) << 2);
      *reinterpret_cast<uint2*>(&Vt[m * 128 + g * 4]) = pack4(acc);
    }
  }
  __syncthreads();

  // stage 2: out[n][m] = sum_i' Fh[i'][n] * V[i'][m]; tiles (nt=2w..2w+1, mt 0..7)
  float* op = out + (size_t)img * (NH * NW);
  for (int nn = 0; nn < 2; ++nn) {
    const int nt = 2 * w + nn;
    s8v a[3];
#pragma unroll
    for (int ks = 0; ks < 3; ++ks) a[ks] = T4[(nt * 3 + ks) * 64 + l];
    for (int mt = 0; mt < 8; ++mt) {
      int m = mt * 16 + lr;
      f4v acc = {0.f, 0.f, 0.f, 0.f};
#pragma unroll
      for (int ks = 0; ks < 3; ++ks) {
        int g = (ks * 8 + lg * 2) ^ ((m & 7) << 2);
        s8v bb = *reinterpret_cast<const s8v*>(&Vt[m * 128 + g * 4]);
        acc = __builtin_amdgcn_mfma_f32_16x16x32_bf16(a[ks], bb, acc, 0, 0, 0);
      }
      int n = nt * 16 + lg * 4;
#pragma unroll
      for (int r = 0; r < 4; ++r) op[(n + r) * NW + m] = acc[r];
    }
  }
}

// ---------------------------------------------------------------- launch
extern "C" void kernel_launch(void* const* d_in, const int* in_sizes, int n_in,
                              void* d_out, int out_size, void* d_ws, size_t ws_size,
                              hipStream_t stream) {
  const float* x  = (const float*)d_in[0];
  const float* wr = (const float*)d_in[1];
  const float* wi = (const float*)d_in[2];
  float* out = (float*)d_out;

  char* ws = (char*)d_ws;
  short* T1 = (short*)(ws);                       // 20480 B
  short* T2 = (short*)(ws + 20480);               // 20480 B
  short* T3 = (short*)(ws + 40960);               // 24576 B
  short* T4 = (short*)(ws + 65536);               // 24576 B
  float2* X2 = (float2*)(ws + 90112);             // 1024*1188*8 = 9,732,096 B
  short* U = (short*)(ws + 90112 + 9732096);      // 1024*7680*2 = 15,728,640 B
  // total ~25.6 MB

  hipLaunchKernelGGL(spc_tables, dim3(176), dim3(256), 0, stream, T1, T2, T3, T4);
  hipLaunchKernelGGL(spc_padU, dim3(NIMG), dim3(256), 0, stream, U);
  hipLaunchKernelGGL(spc_fwd_mfma, dim3(NIMG), dim3(256), 0, stream,
                     x, (const s8v*)T1, (const s8v*)T2, X2);
  hipLaunchKernelGGL(spc_mix, dim3(16, 4, 10), dim3(128), 0, stream, wr, wi, X2, U);
  hipLaunchKernelGGL(spc_inv_mfma, dim3(NIMG), dim3(256), 0, stream,
                     U, (const s8v*)T3, (const s8v*)T4, out);
}